// Round 26
// baseline (53.577 us; speedup 1.0000x reference)
//
#include <hip/hip_runtime.h>
#include <hip/hip_bf16.h>

// FactorizedTrilinear: out[b,z,x,c,dv] = sum_e p1[b,z,dv,e] p2[b,x,dv,e] p3[b,c,dv,e]
// B=4, Z=128, DV=4, IN=512, R=256. Output 4*128^3*4 fp32 = 134 MB.
// R26: store-granularity test. Every prior tri wrote the output in 512B
// chunks (block owned 32 of 128 c); effective write BW pinned at ~3.2-3.4
// TB/s vs fillBuffer's 6.9 (linear) — ratio matches HBM sub-KB chunk
// inefficiency. Now: block = 512 thr = 8 waves = 4dv x 2ct2 covering 64 c;
// per-wave work IDENTICAL to R22 (pv[16]+bq[16] reg-resident, sP1-staged u,
// 16-MFMA chain). Epilogue store instr = 64 lanes x 16B = 1 KB contiguous
// (2x R22). sP1 shared by ct2-pair (+1 barrier after staging). LDS 98 KB ->
// 1 block/CU, 8 waves (same waves/CU as R22). Grid 256 = 1/CU, one round.
// proj = R22 verbatim.

typedef _Float16 f16;
typedef __attribute__((ext_vector_type(8)))  _Float16 f16x8;
typedef __attribute__((ext_vector_type(4)))  float    f32x4;
typedef __attribute__((ext_vector_type(16))) float    f32x16;

// LDS-only barrier: waits local ds ops, does NOT drain global loads/stores.
__device__ __forceinline__ void lds_barrier() {
    __builtin_amdgcn_sched_barrier(0);
    asm volatile("s_waitcnt lgkmcnt(0)" ::: "memory");
    __builtin_amdgcn_s_barrier();
    __builtin_amdgcn_sched_barrier(0);
}

// ---------------- Stage 1: projections via 32x32x16 f16 MFMA (R22 verbatim) ----------------
// Block 128 thr = 2 waves (m-split) -> tile 64m x 32n; grid (32,8,3) = 768
// blocks = 3/CU exact. 16 chunks, dbuf sWt, reg prefetch, lgkm-only barrier.
__global__ __launch_bounds__(128) void proj_kernel(
    const float* __restrict__ x1, const float* __restrict__ x2, const float* __restrict__ x3,
    const float* __restrict__ W1, const float* __restrict__ b1,
    const float* __restrict__ W2, const float* __restrict__ b2,
    const float* __restrict__ W3, const float* __restrict__ b3,
    f16* __restrict__ p1, f16* __restrict__ p2, f16* __restrict__ p3) {
    const int mat = blockIdx.z;
    const float* __restrict__ x    = (mat == 0) ? x1 : (mat == 1) ? x2 : x3;
    const float* __restrict__ W    = (mat == 0) ? W1 : (mat == 1) ? W2 : W3;
    const float* __restrict__ bias = (mat == 0) ? b1 : (mat == 1) ? b2 : b3;
    f16* __restrict__ p = (mat == 0) ? p1 : (mat == 1) ? p2 : p3;

    const int tid  = threadIdx.x;
    const int lane = tid & 63;
    const int w    = tid >> 6;          // wave = m-half
    const int ln   = lane & 31;
    const int kq   = lane >> 5;
    const int m0   = blockIdx.x * 64 + w * 32;
    const int n0b  = blockIdx.y * 32;

    __shared__ f16 sWt[2][32 * 40];     // dbuf [n][k], stride 40 f16

    f32x16 acc;
#pragma unroll
    for (int i = 0; i < 16; ++i) acc[i] = 0.f;

    const int snn = tid & 31, skk0 = tid >> 5;
    const float* Xr = x + (size_t)(m0 + ln) * 512 + kq * 8;

    float wr[8], wr2[8];
    f32x4 xr[4], xn[4];
#pragma unroll
    for (int j = 0; j < 8; ++j)
        wr[j] = W[(size_t)(skk0 + 4 * j) * 256 + n0b + snn];
#pragma unroll
    for (int t = 0; t < 2; ++t) {
        xr[2 * t]     = *(const f32x4*)(Xr + t * 16);
        xr[2 * t + 1] = *(const f32x4*)(Xr + t * 16 + 4);
    }

#pragma unroll 1
    for (int ch = 0; ch < 16; ++ch) {
        const int buf = ch & 1;
#pragma unroll
        for (int j = 0; j < 8; ++j)
            sWt[buf][snn * 40 + skk0 + 4 * j] = (f16)wr[j];
        if (ch < 15) {
            const int k1 = (ch + 1) * 32;
#pragma unroll
            for (int j = 0; j < 8; ++j)
                wr2[j] = W[(size_t)(k1 + skk0 + 4 * j) * 256 + n0b + snn];
#pragma unroll
            for (int t = 0; t < 2; ++t) {
                xn[2 * t]     = *(const f32x4*)(Xr + k1 + t * 16);
                xn[2 * t + 1] = *(const f32x4*)(Xr + k1 + t * 16 + 4);
            }
        }
        lds_barrier();
#pragma unroll
        for (int ks = 0; ks < 2; ++ks) {
            f32x4 a0 = xr[2 * ks], a1 = xr[2 * ks + 1];
            f16x8 av;
            av[0] = (f16)a0[0]; av[1] = (f16)a0[1]; av[2] = (f16)a0[2]; av[3] = (f16)a0[3];
            av[4] = (f16)a1[0]; av[5] = (f16)a1[1]; av[6] = (f16)a1[2]; av[7] = (f16)a1[3];
            f16x8 bv = *(const f16x8*)&sWt[buf][ln * 40 + ks * 16 + kq * 8];
            acc = __builtin_amdgcn_mfma_f32_32x32x16_f16(av, bv, acc, 0, 0, 0);
        }
#pragma unroll
        for (int t = 0; t < 4; ++t) xr[t] = xn[t];
#pragma unroll
        for (int j = 0; j < 8; ++j) wr[j] = wr2[j];
    }

    const int n = n0b + ln;
    const float bn = bias[n];
#pragma unroll
    for (int i = 0; i < 16; ++i) {
        const int m  = m0 + (i & 3) + 8 * (i >> 2) + 4 * kq;
        const int bb = m >> 9, z = (m >> 2) & 127, dv = m & 3;
        p[((bb * 4 + dv) * 128 + z) * 256 + n] = (f16)(acc[i] + bn);
    }
}

// ---------------- Stage 2: trilinear, 64-c blocks (1 KB store chunks) ----------------
// Grid = b(4) x xt(4) x ct(2) x zg(8), zg fastest = 256 blocks = 1/CU exact;
// 512 thr = 8 waves: dv = w&3, ct2 = w>>2. Wave: 32x x 32c x 16z x 1dv,
// c-tile = ct*64 + ct2*32 (block covers 64 c).
// pv[16]+bq[16] full-K register-resident per wave; p1 z-rows in sP1 (32 KB,
// staged by ct2=0 waves, shared by the dv pair). Per z: 16 MFMA ->
// sT[zi&1][dv][x][0..63] (stride 66) -> lgkm-only barrier -> full-wave
// 64-lane f32x4-over-dv PLAIN stores (1 KB contiguous per instruction).
__global__ __launch_bounds__(512) void tri_kernel(
    const f16* __restrict__ p1, const f16* __restrict__ p2,
    const f16* __restrict__ p3, float* __restrict__ out) {
    const int bi = blockIdx.x;
    const int zg = bi & 7;
    const int ct = (bi >> 3) & 1;
    const int xt = (bi >> 4) & 3;
    const int b  = bi >> 6;

    const int tid  = threadIdx.x;
    const int lane = tid & 63;
    const int w    = tid >> 6;          // 0..7
    const int dv   = w & 3;
    const int ct2  = w >> 2;            // c sub-tile within block
    const int ln   = lane & 31;
    const int kq   = lane >> 5;
    const int x0   = xt * 32;
    const int c0w  = ct * 64 + ct2 * 32;   // wave's c-tile base
    const int c0b  = ct * 64;              // block's c base (64 wide)
    const int z0   = zg * 16;
    const int sl   = b * 4 + dv;

    __shared__ __align__(16) f16  sP1[4][16 * 256];  // 32 KB, per-dv (shared by ct2 pair)
    __shared__ float sT[2][4 * 32 * 66];             // 2 x 33 KB transpose buffers

    // ---- stage p1 z-rows: ct2=0 waves only (one per dv) ----
    if (ct2 == 0) {
#pragma unroll
        for (int i = 0; i < 8; ++i) {
            const int G  = i * 64 + lane;
            const int zo = G >> 5, es = G & 31;
            f16x8 v = *(const f16x8*)(p1 + ((sl * 128 + z0 + zo) << 8) + es * 8);
            *(f16x8*)&sP1[dv][G * 8] = v;
        }
    }

    // ---- prologue: full-K fragments in registers (z-invariant) ----
    f16x8 pv[16], bq[16];
    const f16* P2r = p2 + ((sl * 128 + x0 + ln) << 8) + kq * 8;
    const f16* P3r = p3 + ((sl * 128 + c0w + ln) << 8) + kq * 8;
#pragma unroll
    for (int ks = 0; ks < 16; ++ks) {
        pv[ks] = *(const f16x8*)(P2r + ks * 16);
        bq[ks] = *(const f16x8*)(P3r + ks * 16);
    }

    lds_barrier();   // sP1 visible to ct2=1 waves

    const int cl = lane;       // 0..63: c within block's 64
    const int xg = w;          // 0..7: x-group in epilogue

#pragma unroll 1
    for (int zi = 0; zi < 16; ++zi) {
        f32x16 acc;
#pragma unroll
        for (int i = 0; i < 16; ++i) acc[i] = 0.f;

#pragma unroll
        for (int ks = 0; ks < 16; ++ks) {
            f16x8 u = *(const f16x8*)&sP1[dv][(zi * 32 + ks * 2 + kq) * 8];  // broadcast
            f16x8 af = u * pv[ks];        // 4x v_pk_mul_f16
            acc = __builtin_amdgcn_mfma_f32_32x32x16_f16(af, bq[ks], acc, 0, 0, 0);
        }

        // ---- acc -> LDS sT[zi&1][dv][x][ct2*32+ln] (stride 66: conflict-free) ----
        float* T = sT[zi & 1];
#pragma unroll
        for (int i = 0; i < 16; ++i) {
            const int xl = (i & 3) + 8 * (i >> 2) + 4 * kq;
            T[(dv * 32 + xl) * 66 + ct2 * 32 + ln] = acc[i];
        }
        lds_barrier();   // lgkm only: stores from prior iters keep draining

        // ---- transposed read + full-wave 1KB-contiguous PLAIN stores ----
        const int z = z0 + zi;
#pragma unroll
        for (int j = 0; j < 4; ++j) {
            const int xl = xg * 4 + j;
            f32x4 v;
            v[0] = T[(0 * 32 + xl) * 66 + cl];
            v[1] = T[(1 * 32 + xl) * 66 + cl];
            v[2] = T[(2 * 32 + xl) * 66 + cl];
            v[3] = T[(3 * 32 + xl) * 66 + cl];
            const size_t idx = (size_t)((b * 128 + z) * 128 + x0 + xl) * 128 + c0b + cl;
            *(f32x4*)(out + idx * 4) = v;   // plain store: L2 write-back path
        }
        // no second barrier: next iter writes the other sT buffer.
    }
}

extern "C" void kernel_launch(void* const* d_in, const int* in_sizes, int n_in,
                              void* d_out, int out_size, void* d_ws, size_t ws_size,
                              hipStream_t stream) {
    const float* x1 = (const float*)d_in[0];
    const float* x2 = (const float*)d_in[1];
    const float* x3 = (const float*)d_in[2];
    const float* W1 = (const float*)d_in[3];
    const float* b1 = (const float*)d_in[4];
    const float* W2 = (const float*)d_in[5];
    const float* b2 = (const float*)d_in[6];
    const float* W3 = (const float*)d_in[7];
    const float* b3 = (const float*)d_in[8];

    char* ws = (char*)d_ws;
    f16* p1 = (f16*)ws;                            // [16][128][256] f16 = 1 MB
    f16* p2 = (f16*)(ws + (1u << 20));             // 1 MB
    f16* p3 = (f16*)(ws + 2u * (1u << 20));        // 1 MB

    proj_kernel<<<dim3(32, 8, 3), 128, 0, stream>>>(x1, x2, x3, W1, b1, W2, b2, W3, b3,
                                                    p1, p2, p3);
    tri_kernel<<<dim3(256), 512, 0, stream>>>(p1, p2, p3, (float*)d_out);
}

// Round 27
// 51.471 us; speedup vs baseline: 1.0409x; 1.0409x over previous
//
#include <hip/hip_runtime.h>
#include <hip/hip_bf16.h>

// FactorizedTrilinear: out[b,z,x,c,dv] = sum_e p1[b,z,dv,e] p2[b,x,dv,e] p3[b,c,dv,e]
// B=4, Z=128, DV=4, IN=512, R=256. Output 4*128^3*4 fp32 = 134 MB.
// FINAL (= R22, best measured: 51.6 us, reproduced twice; 3.1x over first
// passing version). proj: 32x32x16 f16 MFMA, 64m x 32n tiles, 768 blocks =
// 3/CU exact, dbuf sWt + register prefetch + lgkm-only barriers. tri:
// 16z/block, 512 blocks = 2/CU exact (no tail); per wave (= dv): p1 z-rows
// wave-private in LDS, pv[16]+bq[16] full-K register-resident; per z:
// 16-MFMA chain -> dbuf LDS transpose (stride 33) -> one lgkm-only barrier
// -> coalesced f32x4-over-dv plain stores (never drained mid-loop).
// Falsified levers: occupancy (R12), NT stores (R13), store pacing (R18),
// write locality (R16), scalar merged stores (R19), u-from-global (R10/R20),
// small blocks (R21), producer/consumer (R24), 1KB store chunks (R26).

typedef _Float16 f16;
typedef __attribute__((ext_vector_type(8)))  _Float16 f16x8;
typedef __attribute__((ext_vector_type(4)))  float    f32x4;
typedef __attribute__((ext_vector_type(16))) float    f32x16;

// LDS-only barrier: waits local ds ops, does NOT drain global loads/stores.
__device__ __forceinline__ void lds_barrier() {
    __builtin_amdgcn_sched_barrier(0);
    asm volatile("s_waitcnt lgkmcnt(0)" ::: "memory");
    __builtin_amdgcn_s_barrier();
    __builtin_amdgcn_sched_barrier(0);
}

// ---------------- Stage 1: projections via 32x32x16 f16 MFMA ----------------
// GEMM per matrix: M=2048 (m = b*512 + z*4 + dv), N=256, K=512.
// Block 128 thr = 2 waves (m-split) -> tile 64m x 32n; grid (32,8,3) = 768
// blocks = 3/CU exact. 16 chunks, dbuf sWt, reg prefetch, lgkm-only barrier.
__global__ __launch_bounds__(128) void proj_kernel(
    const float* __restrict__ x1, const float* __restrict__ x2, const float* __restrict__ x3,
    const float* __restrict__ W1, const float* __restrict__ b1,
    const float* __restrict__ W2, const float* __restrict__ b2,
    const float* __restrict__ W3, const float* __restrict__ b3,
    f16* __restrict__ p1, f16* __restrict__ p2, f16* __restrict__ p3) {
    const int mat = blockIdx.z;
    const float* __restrict__ x    = (mat == 0) ? x1 : (mat == 1) ? x2 : x3;
    const float* __restrict__ W    = (mat == 0) ? W1 : (mat == 1) ? W2 : W3;
    const float* __restrict__ bias = (mat == 0) ? b1 : (mat == 1) ? b2 : b3;
    f16* __restrict__ p = (mat == 0) ? p1 : (mat == 1) ? p2 : p3;

    const int tid  = threadIdx.x;
    const int lane = tid & 63;
    const int w    = tid >> 6;          // wave = m-half
    const int ln   = lane & 31;
    const int kq   = lane >> 5;
    const int m0   = blockIdx.x * 64 + w * 32;
    const int n0b  = blockIdx.y * 32;

    __shared__ f16 sWt[2][32 * 40];     // dbuf [n][k], stride 40 f16

    f32x16 acc;
#pragma unroll
    for (int i = 0; i < 16; ++i) acc[i] = 0.f;

    const int snn = tid & 31, skk0 = tid >> 5;
    const float* Xr = x + (size_t)(m0 + ln) * 512 + kq * 8;

    float wr[8], wr2[8];
    f32x4 xr[4], xn[4];
#pragma unroll
    for (int j = 0; j < 8; ++j)
        wr[j] = W[(size_t)(skk0 + 4 * j) * 256 + n0b + snn];
#pragma unroll
    for (int t = 0; t < 2; ++t) {
        xr[2 * t]     = *(const f32x4*)(Xr + t * 16);
        xr[2 * t + 1] = *(const f32x4*)(Xr + t * 16 + 4);
    }

#pragma unroll 1
    for (int ch = 0; ch < 16; ++ch) {
        const int buf = ch & 1;
#pragma unroll
        for (int j = 0; j < 8; ++j)
            sWt[buf][snn * 40 + skk0 + 4 * j] = (f16)wr[j];
        if (ch < 15) {
            const int k1 = (ch + 1) * 32;
#pragma unroll
            for (int j = 0; j < 8; ++j)
                wr2[j] = W[(size_t)(k1 + skk0 + 4 * j) * 256 + n0b + snn];
#pragma unroll
            for (int t = 0; t < 2; ++t) {
                xn[2 * t]     = *(const f32x4*)(Xr + k1 + t * 16);
                xn[2 * t + 1] = *(const f32x4*)(Xr + k1 + t * 16 + 4);
            }
        }
        lds_barrier();
#pragma unroll
        for (int ks = 0; ks < 2; ++ks) {
            f32x4 a0 = xr[2 * ks], a1 = xr[2 * ks + 1];
            f16x8 av;
            av[0] = (f16)a0[0]; av[1] = (f16)a0[1]; av[2] = (f16)a0[2]; av[3] = (f16)a0[3];
            av[4] = (f16)a1[0]; av[5] = (f16)a1[1]; av[6] = (f16)a1[2]; av[7] = (f16)a1[3];
            f16x8 bv = *(const f16x8*)&sWt[buf][ln * 40 + ks * 16 + kq * 8];
            acc = __builtin_amdgcn_mfma_f32_32x32x16_f16(av, bv, acc, 0, 0, 0);
        }
#pragma unroll
        for (int t = 0; t < 4; ++t) xr[t] = xn[t];
#pragma unroll
        for (int j = 0; j < 8; ++j) wr[j] = wr2[j];
    }

    const int n = n0b + ln;
    const float bn = bias[n];
#pragma unroll
    for (int i = 0; i < 16; ++i) {
        const int m  = m0 + (i & 3) + 8 * (i >> 2) + 4 * kq;
        const int bb = m >> 9, z = (m >> 2) & 127, dv = m & 3;
        p[((bb * 4 + dv) * 128 + z) * 256 + n] = (f16)(acc[i] + bn);
    }
}

// ---------------- Stage 2: trilinear (16 z per block) ----------------
// Grid = b(4) x xt(4) x ct(4) x zg(8), zg fastest = 512 blocks = 2/CU exact;
// 256 thr = 4 waves, wave w = dv. Wave: 32x x 32c x 16z x 1dv.
// pv[16] (p2 x-rows), bq[16] (p3 c-rows): full K=256 in 128 VGPRs, z-invariant.
// p1 z-rows staged in wave-private sP1 (32 KB). Per z: 16 MFMA ->
// sT[zi&1][dv][x][c] (stride 33) -> lgkm-only barrier -> transposed
// f32x4-over-dv PLAIN stores. LDS 65 KB -> 2 blocks/CU, one round, no tail.
__global__ __launch_bounds__(256, 2) void tri_kernel(
    const f16* __restrict__ p1, const f16* __restrict__ p2,
    const f16* __restrict__ p3, float* __restrict__ out) {
    const int bi = blockIdx.x;
    const int zg = bi & 7;
    const int ct = (bi >> 3) & 3;
    const int xt = (bi >> 5) & 3;
    const int b  = bi >> 7;

    const int tid  = threadIdx.x;
    const int lane = tid & 63;
    const int w    = tid >> 6;          // = dv
    const int ln   = lane & 31;
    const int kq   = lane >> 5;
    const int x0   = xt * 32;
    const int c0   = ct * 32;
    const int z0   = zg * 16;
    const int sl   = b * 4 + w;

    __shared__ __align__(16) f16  sP1[4][16 * 256];  // 32 KB, wave-private p1 rows
    __shared__ float sT[2][4 * 32 * 33];             // 2 x 16.5 KB transpose buffers

    // ---- stage this wave's 16 p1 z-rows (wave-private: no barrier) ----
#pragma unroll
    for (int i = 0; i < 8; ++i) {
        const int G  = i * 64 + lane;
        const int zo = G >> 5, es = G & 31;
        f16x8 v = *(const f16x8*)(p1 + ((sl * 128 + z0 + zo) << 8) + es * 8);
        *(f16x8*)&sP1[w][G * 8] = v;
    }

    // ---- prologue: full-K fragments in registers (z-invariant) ----
    f16x8 pv[16], bq[16];
    const f16* P2r = p2 + ((sl * 128 + x0 + ln) << 8) + kq * 8;
    const f16* P3r = p3 + ((sl * 128 + c0 + ln) << 8) + kq * 8;
#pragma unroll
    for (int ks = 0; ks < 16; ++ks) {
        pv[ks] = *(const f16x8*)(P2r + ks * 16);
        bq[ks] = *(const f16x8*)(P3r + ks * 16);
    }

    const int cl = tid & 31, xg = tid >> 5;

#pragma unroll 1
    for (int zi = 0; zi < 16; ++zi) {
        f32x16 acc;
#pragma unroll
        for (int i = 0; i < 16; ++i) acc[i] = 0.f;

#pragma unroll
        for (int ks = 0; ks < 16; ++ks) {
            f16x8 u = *(const f16x8*)&sP1[w][(zi * 32 + ks * 2 + kq) * 8];  // broadcast
            f16x8 af = u * pv[ks];        // 4x v_pk_mul_f16
            acc = __builtin_amdgcn_mfma_f32_32x32x16_f16(af, bq[ks], acc, 0, 0, 0);
        }

        // ---- acc -> LDS sT[zi&1][dv][x][c] (stride 33: conflict-free) ----
        float* T = sT[zi & 1];
#pragma unroll
        for (int i = 0; i < 16; ++i) {
            const int xl = (i & 3) + 8 * (i >> 2) + 4 * kq;
            T[w * 1056 + xl * 33 + ln] = acc[i];
        }
        lds_barrier();   // lgkm only: stores from prior iters keep draining

        // ---- transposed read + coalesced f32x4-over-dv PLAIN stores ----
        const int z = z0 + zi;
#pragma unroll
        for (int j = 0; j < 4; ++j) {
            const int xl = xg * 4 + j;
            f32x4 v;
            v[0] = T[0 * 1056 + xl * 33 + cl];
            v[1] = T[1 * 1056 + xl * 33 + cl];
            v[2] = T[2 * 1056 + xl * 33 + cl];
            v[3] = T[3 * 1056 + xl * 33 + cl];
            const size_t idx = (size_t)((b * 128 + z) * 128 + x0 + xl) * 128 + c0 + cl;
            *(f32x4*)(out + idx * 4) = v;   // plain store: L2 write-back path
        }
        // no second barrier: next iter writes the other sT buffer.
    }
}

extern "C" void kernel_launch(void* const* d_in, const int* in_sizes, int n_in,
                              void* d_out, int out_size, void* d_ws, size_t ws_size,
                              hipStream_t stream) {
    const float* x1 = (const float*)d_in[0];
    const float* x2 = (const float*)d_in[1];
    const float* x3 = (const float*)d_in[2];
    const float* W1 = (const float*)d_in[3];
    const float* b1 = (const float*)d_in[4];
    const float* W2 = (const float*)d_in[5];
    const float* b2 = (const float*)d_in[6];
    const float* W3 = (const float*)d_in[7];
    const float* b3 = (const float*)d_in[8];

    char* ws = (char*)d_ws;
    f16* p1 = (f16*)ws;                            // [16][128][256] f16 = 1 MB
    f16* p2 = (f16*)(ws + (1u << 20));             // 1 MB
    f16* p3 = (f16*)(ws + 2u * (1u << 20));        // 1 MB

    proj_kernel<<<dim3(32, 8, 3), 128, 0, stream>>>(x1, x2, x3, W1, b1, W2, b2, W3, b3,
                                                    p1, p2, p3);
    tri_kernel<<<dim3(512), 256, 0, stream>>>(p1, p2, p3, (float*)d_out);
}